// Round 6
// baseline (167.901 us; speedup 1.0000x reference)
//
#include <hip/hip_runtime.h>
#include <math.h>
#include <stdint.h>

#define N 4096
#define D 512
#define C 128
#define DK (D / 32)          // 16 fragment-chunks along K per rowtile
#define ALPHA 0.0005
#define NCE 64               // 64 CE tiles of 64 rows
#define NCOUNT 1056          // sum over 64 strips of (32 - strip/2) col-tiles
#define NBLK (NCE + NCOUNT)  // 1120 = 8 * 140 (bijective XCD swizzle)

typedef __bf16 bf16x8 __attribute__((ext_vector_type(8)));
typedef float f32x4 __attribute__((ext_vector_type(4)));

// ---------------------------------------------------------------------------
// Fragment-major layout: for rowtile rt (16 rows) and k-chunk kt (32 k),
// a 1 KB chunk at elem offset ((rt*DK + kt) << 9) holds the MFMA fragment in
// exact lane order: lane l <-> row rt*16+(l&15), k kt*32+(l>>4)*8+j.
// A- and B-operand lane layouts of mfma_f32_16x16x32_bf16 coincide, so the
// same chunk serves either side.  Every fragment load in the GEMM is then a
// single wave-uniform-base global_load_dwordx4 (64 lanes x 16B = contiguous
// 1 KB): perfectly coalesced, straight from L2/L3.  No LDS, no barriers.
// ---------------------------------------------------------------------------

// prep: blocks [0,N/4)     : 4 rows/block, 1 wave/row: sq, dot0, dyrow,
//                            xb2 fragment-major bf16, cnt=0
//       blocks [N/4,N/4+8) : Wtb2 fragment-major (col-tiles of W^T) via LDS;
//                            block 0 zeroes dacc/done.
__global__ __launch_bounds__(256) void prep_kernel(const float* __restrict__ x,
                                                   const float* __restrict__ Y,
                                                   const float* __restrict__ W,
                                                   float* __restrict__ sq,
                                                   float* __restrict__ dot0,
                                                   float* __restrict__ dyrow,
                                                   __bf16* __restrict__ xb2,
                                                   __bf16* __restrict__ Wtb2,
                                                   unsigned* __restrict__ cnt,
                                                   double* __restrict__ dacc,
                                                   unsigned* __restrict__ done) {
    const int t = threadIdx.x;
    if (blockIdx.x >= N / 4) {
        __shared__ float wlds[64 * 128];      // 32 KB: W rows [kb, kb+64)
        const int bb = blockIdx.x - N / 4;    // 0..7
        const int kb = bb * 64;
#pragma unroll
        for (int s = 0; s < 8; ++s) {
            const int e = t + 256 * s;        // float4 index 0..2047
            ((float4*)wlds)[e] = ((const float4*)(W + (size_t)kb * C))[e];
        }
        __syncthreads();
        // tasks: tau = (ct*2 + ktl)*64 + lane ; chunk (ct, kt=2bb+ktl)
#pragma unroll
        for (int s = 0; s < 4; ++s) {
            const int tau = t + 256 * s;      // 0..1023
            const int lq = tau & 63, q = tau >> 6;
            const int ct = q >> 1, ktl = q & 1;
            const int kgl = lq >> 4, lr2 = lq & 15;
            bf16x8 o;
#pragma unroll
            for (int j = 0; j < 8; ++j)
                o[j] = (__bf16)wlds[(ktl * 32 + kgl * 8 + j) * 128 + ct * 16 + lr2];
            *(bf16x8*)(Wtb2 + (((size_t)(ct * DK + (2 * bb + ktl))) << 9) + lq * 8) = o;
        }
        if (bb == 0 && t == 0) { dacc[0] = 0.0; *done = 0u; }
        return;
    }
    const int i = blockIdx.x * 4 + (t >> 6);
    const int l = t & 63;
    const float* xp = x + (size_t)i * D + l * 8;
    const float4 v0 = *(const float4*)(xp);
    const float4 v1 = *(const float4*)(xp + 4);
    const float4 u0 = *(const float4*)(x + l * 8);
    const float4 u1 = *(const float4*)(x + l * 8 + 4);
    float s1 = v0.x * v0.x + v0.y * v0.y + v0.z * v0.z + v0.w * v0.w
             + v1.x * v1.x + v1.y * v1.y + v1.z * v1.z + v1.w * v1.w;
    float s2 = v0.x * u0.x + v0.y * u0.y + v0.z * u0.z + v0.w * u0.w
             + v1.x * u1.x + v1.y * u1.y + v1.z * u1.z + v1.w * u1.w;
    bf16x8 o;
    o[0] = (__bf16)v0.x; o[1] = (__bf16)v0.y; o[2] = (__bf16)v0.z; o[3] = (__bf16)v0.w;
    o[4] = (__bf16)v1.x; o[5] = (__bf16)v1.y; o[6] = (__bf16)v1.z; o[7] = (__bf16)v1.w;
    // thread l holds row i, elems [l*8, l*8+8) = k-chunk kt=l>>2, k-group kg=l&3
    {
        const int rt = i >> 4, lrr = i & 15;
        const int kt = l >> 2, kg = l & 3;
        *(bf16x8*)(xb2 + (((size_t)(rt * DK + kt)) << 9) + (kg * 16 + lrr) * 8) = o;
    }
    // Y-row distance to Y_0: lane l handles cols 2l, 2l+1
    const float2 yv  = *(const float2*)(Y + (size_t)i * C + l * 2);
    const float2 y0v = *(const float2*)(Y + l * 2);
    const float ex = yv.x - y0v.x, ey = yv.y - y0v.y;
    float d2 = ex * ex + ey * ey;
    for (int off = 32; off; off >>= 1) {
        s1 += __shfl_down(s1, off);
        s2 += __shfl_down(s2, off);
        d2 += __shfl_down(d2, off);
    }
    if (l == 0) { sq[i] = s1; dot0[i] = s2; cnt[i] = 0u; dyrow[i] = d2; }
}

// ---------------------------------------------------------------------------
// fused_mfma: 64x128 output tiles, 1120 blocks, 256 threads, ZERO main-loop
// LDS.  Per wave, per kt (16 total): 2 A-fragment + 4 B-fragment coalesced
// 1KB loads from the fragment-major arrays + 8 MFMA.  Fully unrolled; the
// compiler pipelines loads under MFMA via vmcnt; 12 barrier-free waves/CU
// hide L2 latency.  (Rounds 0-5: the stage->drain->compute LDS structure
// phase-locked blocks and capped LDS-fill at 2-5 TB/s; this reads ~430 MB
// straight from L2 at line granularity, floor ~12.5 us.)
//   count tiles: strip si (64 rows at bi=64*si), col tile cj >= si/2.
//     edge (cj==si/2, contains diagonal): guarded count, no col-update.
//     strictly-upper: unguarded row-update + col-update (i!=0 guard).
//   CE tiles: 64 rows x 128 logits vs Wtb2, log-softmax, pick y[i],
//     f64 partial -> atomicAdd(dacc).
//   Last block (done counter): final reduction over cnt/dyrow/y -> out[0].
// ---------------------------------------------------------------------------
__global__ __launch_bounds__(256, 3) void fused_mfma(const __bf16* __restrict__ xb2,
                                                     const __bf16* __restrict__ Wtb2,
                                                     const float* __restrict__ sq,
                                                     const float* __restrict__ dot0,
                                                     const int* __restrict__ y,
                                                     const float* __restrict__ b,
                                                     const float* __restrict__ dyrow,
                                                     unsigned* __restrict__ cnt,
                                                     double* __restrict__ dacc,
                                                     unsigned* __restrict__ done,
                                                     float* __restrict__ out) {
    __shared__ float rmax[64][2];
    __shared__ float rsum[64][2];
    __shared__ double dred[4];
    __shared__ unsigned lastflag;

    const int t = threadIdx.x;
    const int w = t >> 6, l = t & 63;
    const int wy = w >> 1, wx = w & 1;
    const int kg = l >> 4, lr = l & 15;

    // bijective XCD swizzle (1120 = 8*140)
    const int bid = (int)blockIdx.x;
    const int L = (bid & 7) * (NBLK / 8) + (bid >> 3);

    const bool isCE = (L < NCE);
    int bi, bj;
    bool edge = false;
    if (isCE) {
        bi = L * 64;
        bj = 0;
    } else {
        int si = 0, rem = L - NCE;
        while (rem >= 32 - (si >> 1)) { rem -= 32 - (si >> 1); ++si; }
        const int cj = (si >> 1) + rem;
        bi = si * 64;
        bj = cj * 128;
        edge = (rem == 0);
    }

    f32x4 acc[2][4];
    const f32x4 zero = {0.f, 0.f, 0.f, 0.f};
#pragma unroll
    for (int mt = 0; mt < 2; ++mt)
#pragma unroll
        for (int nt = 0; nt < 4; ++nt) acc[mt][nt] = zero;

    // wave's fragment rowtiles: A rows wy*32 + mt*16 ; B cols wx*64 + nt*16
    const int rtA0 = (bi >> 4) + wy * 2;
    const int rtB0 = (isCE ? 0 : (bj >> 4)) + wx * 4;
    const __bf16* Bp = isCE ? Wtb2 : xb2;
    const int lo8 = l * 8;   // lane's 16B slot within each 1KB chunk

#pragma unroll
    for (int kt = 0; kt < DK; ++kt) {
        bf16x8 av[2], bv[4];
#pragma unroll
        for (int mt = 0; mt < 2; ++mt)
            av[mt] = *(const bf16x8*)(xb2 + (((size_t)((rtA0 + mt) * DK + kt)) << 9) + lo8);
#pragma unroll
        for (int nt = 0; nt < 4; ++nt)
            bv[nt] = *(const bf16x8*)(Bp + (((size_t)((rtB0 + nt) * DK + kt)) << 9) + lo8);
#pragma unroll
        for (int mt = 0; mt < 2; ++mt)
#pragma unroll
            for (int nt = 0; nt < 4; ++nt)
                acc[mt][nt] = __builtin_amdgcn_mfma_f32_16x16x32_bf16(
                    av[mt], bv[nt], acc[mt][nt], 0, 0, 0);
    }

    if (isCE) {
        // ---- CE epilogue: log-softmax over 128 cols, pick col y[i] ----
        int jn[4]; float bb4[4];
#pragma unroll
        for (int nt = 0; nt < 4; ++nt) { jn[nt] = wx * 64 + nt * 16 + lr; bb4[nt] = b[jn[nt]]; }
#pragma unroll
        for (int mt = 0; mt < 2; ++mt)
#pragma unroll
            for (int r = 0; r < 4; ++r) {
                float m = acc[mt][0][r] + bb4[0];
#pragma unroll
                for (int nt = 1; nt < 4; ++nt) m = fmaxf(m, acc[mt][nt][r] + bb4[nt]);
                m = fmaxf(m, __shfl_xor(m, 1));
                m = fmaxf(m, __shfl_xor(m, 2));
                m = fmaxf(m, __shfl_xor(m, 4));
                m = fmaxf(m, __shfl_xor(m, 8));
                if (lr == 0) rmax[wy * 32 + mt * 16 + kg * 4 + r][wx] = m;
            }
        __syncthreads();
        float mrow[2][4];
#pragma unroll
        for (int mt = 0; mt < 2; ++mt)
#pragma unroll
            for (int r = 0; r < 4; ++r) {
                const int ri = wy * 32 + mt * 16 + kg * 4 + r;
                mrow[mt][r] = fmaxf(rmax[ri][0], rmax[ri][1]);
                float s = 0.f;
#pragma unroll
                for (int nt = 0; nt < 4; ++nt) s += expf(acc[mt][nt][r] + bb4[nt] - mrow[mt][r]);
                s += __shfl_xor(s, 1);
                s += __shfl_xor(s, 2);
                s += __shfl_xor(s, 4);
                s += __shfl_xor(s, 8);
                if (lr == 0) rsum[ri][wx] = s;
            }
        __syncthreads();
        double myloss = 0.0;
#pragma unroll
        for (int mt = 0; mt < 2; ++mt)
#pragma unroll
            for (int r = 0; r < 4; ++r) {
                const int ri = wy * 32 + mt * 16 + kg * 4 + r;
                const int i = bi + ri;
                const float s = rsum[ri][0] + rsum[ri][1];
                const int yi = y[i];
#pragma unroll
                for (int nt = 0; nt < 4; ++nt)
                    if (jn[nt] == yi)
                        myloss -= (double)(acc[mt][nt][r] + bb4[nt] - mrow[mt][r] - logf(s));
            }
        for (int o = 32; o; o >>= 1) myloss += __shfl_down(myloss, o);
        if (l == 0) dred[w] = myloss;
        __syncthreads();
        if (t == 0) atomicAdd(&dacc[0], dred[0] + dred[1] + dred[2] + dred[3]);
    } else {
        // ---- count epilogue ----
        const float sq0v = sq[0];
        int jn[4]; float sqj[4], thrj[4];
#pragma unroll
        for (int nt = 0; nt < 4; ++nt) {
            jn[nt] = bj + wx * 64 + nt * 16 + lr;
            sqj[nt] = sq[jn[nt]];
            thrj[nt] = sq0v - 2.0f * dot0[jn[nt]];
        }
        unsigned cja[4] = {0u, 0u, 0u, 0u};
#pragma unroll
        for (int mt = 0; mt < 2; ++mt)
#pragma unroll
            for (int r = 0; r < 4; ++r) {
                const int i = bi + wy * 32 + mt * 16 + kg * 4 + r;
                const float thri = sq0v - 2.0f * dot0[i];
                const float sqi = sq[i];
                unsigned ci = 0;
                if (edge) {
#pragma unroll
                    for (int nt = 0; nt < 4; ++nt) {
                        const float d = acc[mt][nt][r];
                        const int j = jn[nt];
                        if (sqj[nt] - 2.0f * d < thri && j != i && j != 0) ++ci;
                    }
                } else {
                    // strictly upper: j >= bi+64 > i and j >= 128 > 0
#pragma unroll
                    for (int nt = 0; nt < 4; ++nt) {
                        const float d = acc[mt][nt][r];
                        if (sqj[nt] - 2.0f * d < thri) ++ci;
                        if (sqi - 2.0f * d < thrj[nt] && i != 0) ++cja[nt];
                    }
                }
                ci += __shfl_xor((int)ci, 1);
                ci += __shfl_xor((int)ci, 2);
                ci += __shfl_xor((int)ci, 4);
                ci += __shfl_xor((int)ci, 8);
                if (lr == 0 && ci) atomicAdd(&cnt[i], ci);
            }
        if (!edge) {
#pragma unroll
            for (int nt = 0; nt < 4; ++nt) {
                unsigned v = cja[nt];
                v += __shfl_xor((int)v, 16);
                v += __shfl_xor((int)v, 32);
                if (l < 16 && v) atomicAdd(&cnt[jn[nt]], v);
            }
        }
    }

    // ---- last-block finalize ----
    __threadfence();
    __syncthreads();
    if (t == 0) lastflag = (atomicAdd(done, 1u) == NBLK - 1) ? 1u : 0u;
    __syncthreads();
    if (lastflag) {
        __threadfence();
        const int y0 = y[0];
        double regs = 0.0;
#pragma unroll 1
        for (int s = 0; s < 16; ++s) {
            const int i = t + 256 * s;
            if (i > 0 && y[i] == y0) {
                // atomic RMW read: coherent with the count blocks' atomicAdds
                const unsigned c = atomicAdd(&cnt[i], 0u);
                if (c <= 1u) regs += sqrt((double)fmaxf(dyrow[i], 0.f));
            }
        }
        for (int o = 32; o; o >>= 1) regs += __shfl_down(regs, o);
        if (l == 0) dred[w] = regs;
        __syncthreads();
        if (t == 0) {
            const double Lsum = atomicAdd(&dacc[0], 0.0);
            out[0] = (float)(Lsum / (double)N + ALPHA * (dred[0] + dred[1] + dred[2] + dred[3]));
        }
    }
}

// ---------------------------------------------------------------------------
extern "C" void kernel_launch(void* const* d_in, const int* in_sizes, int n_in,
                              void* d_out, int out_size, void* d_ws, size_t ws_size,
                              hipStream_t stream) {
    const float* x  = (const float*)d_in[0];   // (N, D)
    const int*   y  = (const int*)d_in[1];     // (N,)
    const float* Y  = (const float*)d_in[2];   // (N, C)
    const float* W  = (const float*)d_in[3];   // (D, C)
    const float* b  = (const float*)d_in[4];   // (C,)
    float* out = (float*)d_out;

    float* wsf      = (float*)d_ws;
    float* sq       = wsf;                       // N f32
    float* dot0     = wsf + N;                   // N f32
    float* dyrow    = wsf + 2 * N;               // N f32 (||Yi-Y0||^2)
    unsigned* cnt   = (unsigned*)(wsf + 3 * N);  // N u32
    __bf16* xb2     = (__bf16*)(wsf + 4 * N);    // N*D bf16, fragment-major (4 MB)
    __bf16* Wtb2    = (__bf16*)((char*)xb2 + (size_t)N * D * 2); // C*D bf16, frag-major
    double* dacc    = (double*)((char*)Wtb2 + (size_t)C * D * 2);
    unsigned* done  = (unsigned*)(dacc + 2);

    prep_kernel<<<N / 4 + 8, 256, 0, stream>>>(x, Y, W, sq, dot0, dyrow, xb2, Wtb2, cnt, dacc, done);
    fused_mfma<<<NBLK, 256, 0, stream>>>(xb2, Wtb2, sq, dot0, y, b, dyrow, cnt, dacc, done, out);
}

// Round 7
// 131.555 us; speedup vs baseline: 1.2763x; 1.2763x over previous
//
#include <hip/hip_runtime.h>
#include <math.h>
#include <stdint.h>

#define N 4096
#define D 512
#define C 128
#define DK (D / 32)          // 16 fragment-chunks along K per rowtile
#define ALPHA 0.0005
#define NCE 32               // 32 CE tiles of 128 rows
#define NCOUNT 528           // upper-tri incl diag of 32x32 grid of 128x128 tiles
#define NBLK (NCE + NCOUNT)  // 560 = 8 * 70 (bijective XCD swizzle)

typedef __bf16 bf16x8 __attribute__((ext_vector_type(8)));
typedef float f32x4 __attribute__((ext_vector_type(4)));

// ---------------------------------------------------------------------------
// Fragment-major layout: for rowtile rt (16 rows) and k-chunk kt (32 k),
// a 1 KB chunk at elem offset ((rt*DK + kt) << 9) holds the MFMA fragment in
// exact lane order: lane l <-> row rt*16+(l&15), k kt*32+(l>>4)*8+j.
// A- and B-operand lane layouts of mfma_f32_16x16x32_bf16 coincide, so the
// same chunk serves either side.  Every fragment load is a wave-uniform-base
// global_load_dwordx4 (64 lanes x 16B = contiguous 1 KB), straight from L2.
// ---------------------------------------------------------------------------

// prep: blocks [0,N/4)     : 4 rows/block, 1 wave/row: sq, dot0, dyrow,
//                            xb2 fragment-major bf16, cnt=0
//       blocks [N/4,N/4+8) : Wtb2 fragment-major (col-tiles of W^T) via LDS;
//                            block 0 zeroes dacc/done.
__global__ __launch_bounds__(256) void prep_kernel(const float* __restrict__ x,
                                                   const float* __restrict__ Y,
                                                   const float* __restrict__ W,
                                                   float* __restrict__ sq,
                                                   float* __restrict__ dot0,
                                                   float* __restrict__ dyrow,
                                                   __bf16* __restrict__ xb2,
                                                   __bf16* __restrict__ Wtb2,
                                                   unsigned* __restrict__ cnt,
                                                   double* __restrict__ dacc,
                                                   unsigned* __restrict__ done) {
    const int t = threadIdx.x;
    if (blockIdx.x >= N / 4) {
        __shared__ float wlds[64 * 128];      // 32 KB: W rows [kb, kb+64)
        const int bb = blockIdx.x - N / 4;    // 0..7
        const int kb = bb * 64;
#pragma unroll
        for (int s = 0; s < 8; ++s) {
            const int e = t + 256 * s;        // float4 index 0..2047
            ((float4*)wlds)[e] = ((const float4*)(W + (size_t)kb * C))[e];
        }
        __syncthreads();
        // tasks: tau = (ct*2 + ktl)*64 + lane ; chunk (ct, kt=2bb+ktl)
#pragma unroll
        for (int s = 0; s < 4; ++s) {
            const int tau = t + 256 * s;      // 0..1023
            const int lq = tau & 63, q = tau >> 6;
            const int ct = q >> 1, ktl = q & 1;
            const int kgl = lq >> 4, lr2 = lq & 15;
            bf16x8 o;
#pragma unroll
            for (int j = 0; j < 8; ++j)
                o[j] = (__bf16)wlds[(ktl * 32 + kgl * 8 + j) * 128 + ct * 16 + lr2];
            *(bf16x8*)(Wtb2 + (((size_t)(ct * DK + (2 * bb + ktl))) << 9) + lq * 8) = o;
        }
        if (bb == 0 && t == 0) { dacc[0] = 0.0; *done = 0u; }
        return;
    }
    const int i = blockIdx.x * 4 + (t >> 6);
    const int l = t & 63;
    const float* xp = x + (size_t)i * D + l * 8;
    const float4 v0 = *(const float4*)(xp);
    const float4 v1 = *(const float4*)(xp + 4);
    const float4 u0 = *(const float4*)(x + l * 8);
    const float4 u1 = *(const float4*)(x + l * 8 + 4);
    float s1 = v0.x * v0.x + v0.y * v0.y + v0.z * v0.z + v0.w * v0.w
             + v1.x * v1.x + v1.y * v1.y + v1.z * v1.z + v1.w * v1.w;
    float s2 = v0.x * u0.x + v0.y * u0.y + v0.z * u0.z + v0.w * u0.w
             + v1.x * u1.x + v1.y * u1.y + v1.z * u1.z + v1.w * u1.w;
    bf16x8 o;
    o[0] = (__bf16)v0.x; o[1] = (__bf16)v0.y; o[2] = (__bf16)v0.z; o[3] = (__bf16)v0.w;
    o[4] = (__bf16)v1.x; o[5] = (__bf16)v1.y; o[6] = (__bf16)v1.z; o[7] = (__bf16)v1.w;
    // thread l holds row i, elems [l*8, l*8+8) = k-chunk kt=l>>2, k-group kg=l&3
    {
        const int rt = i >> 4, lrr = i & 15;
        const int kt = l >> 2, kg = l & 3;
        *(bf16x8*)(xb2 + (((size_t)(rt * DK + kt)) << 9) + (kg * 16 + lrr) * 8) = o;
    }
    // Y-row distance to Y_0: lane l handles cols 2l, 2l+1
    const float2 yv  = *(const float2*)(Y + (size_t)i * C + l * 2);
    const float2 y0v = *(const float2*)(Y + l * 2);
    const float ex = yv.x - y0v.x, ey = yv.y - y0v.y;
    float d2 = ex * ex + ey * ey;
    for (int off = 32; off; off >>= 1) {
        s1 += __shfl_down(s1, off);
        s2 += __shfl_down(s2, off);
        d2 += __shfl_down(d2, off);
    }
    if (l == 0) { sq[i] = s1; dot0[i] = s2; cnt[i] = 0u; dyrow[i] = d2; }
}

// ---------------------------------------------------------------------------
// fused_mfma: 128x128 output tiles, 560 blocks, 256 threads (4 waves as 2x2,
// each wave owns a 64x64 sub-tile: acc[4][4], 16 MFMA per kt).  ZERO
// main-loop LDS/barriers.  Explicit 1-deep register prefetch with statically
// named double buffers (a0/b0, a1/b1): loads for kt+1 are issued before the
// MFMAs of kt, so the compiler's counted vmcnt keeps ~8 KB/wave in flight
// under compute.  (R6 post-mortem: VGPR_Count=44 proved the compiler built
// NO pipeline -- one full L2 round-trip exposed per kt per wave.  This
// round forces the pipeline and also 3x-reduces L2 traffic: 143 MB total,
// per-CU floor ~11 us at m97's measured 22 B/cyc/CU L2 rate.)
//   count tiles: strip si (128 rows), col tile cj >= si.
//     diag (cj==si): guarded row-counts only (j!=i, j!=0).
//     cj>si: unguarded row-counts + col-counts (i!=0 guard).
//   CE tiles (L<32): 128 rows x 128 logits vs Wtb2, log-softmax, pick y[i],
//     f64 partial -> atomicAdd(dacc).
//   Last block (done counter): final reduction over cnt/dyrow/y -> out[0].
// ---------------------------------------------------------------------------
__global__ __launch_bounds__(256, 3) void fused_mfma(const __bf16* __restrict__ xb2,
                                                     const __bf16* __restrict__ Wtb2,
                                                     const float* __restrict__ sq,
                                                     const float* __restrict__ dot0,
                                                     const int* __restrict__ y,
                                                     const float* __restrict__ b,
                                                     const float* __restrict__ dyrow,
                                                     unsigned* __restrict__ cnt,
                                                     double* __restrict__ dacc,
                                                     unsigned* __restrict__ done,
                                                     float* __restrict__ out) {
    __shared__ float rmax[128][2];
    __shared__ float rsum[128][2];
    __shared__ double dred[4];
    __shared__ unsigned lastflag;

    const int t = threadIdx.x;
    const int w = t >> 6, l = t & 63;
    const int wy = w >> 1, wx = w & 1;
    const int kg = l >> 4, lr = l & 15;

    // bijective XCD swizzle (560 = 8*70)
    const int bid = (int)blockIdx.x;
    const int L = (bid & 7) * (NBLK / 8) + (bid >> 3);

    const bool isCE = (L < NCE);
    int bi, bj;
    bool diag = false;
    if (isCE) {
        bi = L * 128;
        bj = 0;
    } else {
        int si = 0, rem = L - NCE;
        while (rem >= 32 - si) { rem -= 32 - si; ++si; }
        bi = si * 128;
        bj = (si + rem) * 128;
        diag = (rem == 0);
    }

    f32x4 acc[4][4];
    const f32x4 zero = {0.f, 0.f, 0.f, 0.f};
#pragma unroll
    for (int mt = 0; mt < 4; ++mt)
#pragma unroll
        for (int nt = 0; nt < 4; ++nt) acc[mt][nt] = zero;

    // wave's fragment rowtiles: A rows wy*64 + mt*16 ; B cols wx*64 + nt*16
    const int rtA0 = (bi >> 4) + wy * 4;
    const int rtB0 = (isCE ? 0 : (bj >> 4)) + wx * 4;
    const __bf16* Bp = isCE ? Wtb2 : xb2;
    const int lo8 = l * 8;   // lane's 16B slot within each 1KB chunk

    bf16x8 a0[4], b0[4], a1[4], b1[4];
#define LOADF(AV, BV, KT)                                                          \
    do {                                                                           \
        _Pragma("unroll") for (int q = 0; q < 4; ++q)                              \
            AV[q] = *(const bf16x8*)(xb2 + (((size_t)((rtA0 + q) * DK + (KT))) << 9) + lo8); \
        _Pragma("unroll") for (int q = 0; q < 4; ++q)                              \
            BV[q] = *(const bf16x8*)(Bp + (((size_t)((rtB0 + q) * DK + (KT))) << 9) + lo8);  \
    } while (0)
#define MFMAF(AV, BV)                                                              \
    do {                                                                           \
        _Pragma("unroll") for (int mt = 0; mt < 4; ++mt)                           \
            _Pragma("unroll") for (int nt = 0; nt < 4; ++nt)                       \
                acc[mt][nt] = __builtin_amdgcn_mfma_f32_16x16x32_bf16(             \
                    AV[mt], BV[nt], acc[mt][nt], 0, 0, 0);                         \
    } while (0)

    LOADF(a0, b0, 0);
#pragma unroll
    for (int k2 = 0; k2 < 8; ++k2) {
        LOADF(a1, b1, 2 * k2 + 1);     // prefetch kt+1 before computing kt
        MFMAF(a0, b0);
        if (k2 < 7) LOADF(a0, b0, 2 * k2 + 2);
        MFMAF(a1, b1);
    }
#undef LOADF
#undef MFMAF

    if (isCE) {
        // ---- CE epilogue: log-softmax over 128 cols, pick col y[i] ----
        int jn[4]; float bb4[4];
#pragma unroll
        for (int nt = 0; nt < 4; ++nt) { jn[nt] = wx * 64 + nt * 16 + lr; bb4[nt] = b[jn[nt]]; }
#pragma unroll
        for (int mt = 0; mt < 4; ++mt)
#pragma unroll
            for (int r = 0; r < 4; ++r) {
                float m = acc[mt][0][r] + bb4[0];
#pragma unroll
                for (int nt = 1; nt < 4; ++nt) m = fmaxf(m, acc[mt][nt][r] + bb4[nt]);
                m = fmaxf(m, __shfl_xor(m, 1));
                m = fmaxf(m, __shfl_xor(m, 2));
                m = fmaxf(m, __shfl_xor(m, 4));
                m = fmaxf(m, __shfl_xor(m, 8));
                if (lr == 0) rmax[wy * 64 + mt * 16 + kg * 4 + r][wx] = m;
            }
        __syncthreads();
        float mrow[4][4];
#pragma unroll
        for (int mt = 0; mt < 4; ++mt)
#pragma unroll
            for (int r = 0; r < 4; ++r) {
                const int ri = wy * 64 + mt * 16 + kg * 4 + r;
                mrow[mt][r] = fmaxf(rmax[ri][0], rmax[ri][1]);
                float s = 0.f;
#pragma unroll
                for (int nt = 0; nt < 4; ++nt) s += expf(acc[mt][nt][r] + bb4[nt] - mrow[mt][r]);
                s += __shfl_xor(s, 1);
                s += __shfl_xor(s, 2);
                s += __shfl_xor(s, 4);
                s += __shfl_xor(s, 8);
                if (lr == 0) rsum[ri][wx] = s;
            }
        __syncthreads();
        double myloss = 0.0;
#pragma unroll
        for (int mt = 0; mt < 4; ++mt)
#pragma unroll
            for (int r = 0; r < 4; ++r) {
                const int ri = wy * 64 + mt * 16 + kg * 4 + r;
                const int i = bi + ri;
                const float s = rsum[ri][0] + rsum[ri][1];
                const int yi = y[i];
#pragma unroll
                for (int nt = 0; nt < 4; ++nt)
                    if (jn[nt] == yi)
                        myloss -= (double)(acc[mt][nt][r] + bb4[nt] - mrow[mt][r] - logf(s));
            }
        for (int o = 32; o; o >>= 1) myloss += __shfl_down(myloss, o);
        if (l == 0) dred[w] = myloss;
        __syncthreads();
        if (t == 0) atomicAdd(&dacc[0], dred[0] + dred[1] + dred[2] + dred[3]);
    } else {
        // ---- count epilogue ----
        const float sq0v = sq[0];
        int jn[4]; float sqj[4], thrj[4];
#pragma unroll
        for (int nt = 0; nt < 4; ++nt) {
            jn[nt] = bj + wx * 64 + nt * 16 + lr;
            sqj[nt] = sq[jn[nt]];
            thrj[nt] = sq0v - 2.0f * dot0[jn[nt]];
        }
        unsigned cja[4] = {0u, 0u, 0u, 0u};
#pragma unroll
        for (int mt = 0; mt < 4; ++mt)
#pragma unroll
            for (int r = 0; r < 4; ++r) {
                const int i = bi + wy * 64 + mt * 16 + kg * 4 + r;
                const float thri = sq0v - 2.0f * dot0[i];
                const float sqi = sq[i];
                unsigned ci = 0;
                if (diag) {
#pragma unroll
                    for (int nt = 0; nt < 4; ++nt) {
                        const float d = acc[mt][nt][r];
                        const int j = jn[nt];
                        if (sqj[nt] - 2.0f * d < thri && j != i && j != 0) ++ci;
                    }
                } else {
                    // strictly upper: j >= bj >= bi+128 > i and j >= 128 > 0
#pragma unroll
                    for (int nt = 0; nt < 4; ++nt) {
                        const float d = acc[mt][nt][r];
                        if (sqj[nt] - 2.0f * d < thri) ++ci;
                        if (sqi - 2.0f * d < thrj[nt] && i != 0) ++cja[nt];
                    }
                }
                ci += __shfl_xor((int)ci, 1);
                ci += __shfl_xor((int)ci, 2);
                ci += __shfl_xor((int)ci, 4);
                ci += __shfl_xor((int)ci, 8);
                if (lr == 0 && ci) atomicAdd(&cnt[i], ci);
            }
        if (!diag) {
#pragma unroll
            for (int nt = 0; nt < 4; ++nt) {
                unsigned v = cja[nt];
                v += __shfl_xor((int)v, 16);
                v += __shfl_xor((int)v, 32);
                if (l < 16 && v) atomicAdd(&cnt[jn[nt]], v);
            }
        }
    }

    // ---- last-block finalize ----
    __threadfence();
    __syncthreads();
    if (t == 0) lastflag = (atomicAdd(done, 1u) == NBLK - 1) ? 1u : 0u;
    __syncthreads();
    if (lastflag) {
        __threadfence();
        const int y0 = y[0];
        double regs = 0.0;
#pragma unroll 1
        for (int s = 0; s < 16; ++s) {
            const int i = t + 256 * s;
            if (i > 0 && y[i] == y0) {
                // atomic RMW read: coherent with the count blocks' atomicAdds
                const unsigned c = atomicAdd(&cnt[i], 0u);
                if (c <= 1u) regs += sqrt((double)fmaxf(dyrow[i], 0.f));
            }
        }
        for (int o = 32; o; o >>= 1) regs += __shfl_down(regs, o);
        if (l == 0) dred[w] = regs;
        __syncthreads();
        if (t == 0) {
            const double Lsum = atomicAdd(&dacc[0], 0.0);
            out[0] = (float)(Lsum / (double)N + ALPHA * (dred[0] + dred[1] + dred[2] + dred[3]));
        }
    }
}

// ---------------------------------------------------------------------------
extern "C" void kernel_launch(void* const* d_in, const int* in_sizes, int n_in,
                              void* d_out, int out_size, void* d_ws, size_t ws_size,
                              hipStream_t stream) {
    const float* x  = (const float*)d_in[0];   // (N, D)
    const int*   y  = (const int*)d_in[1];     // (N,)
    const float* Y  = (const float*)d_in[2];   // (N, C)
    const float* W  = (const float*)d_in[3];   // (D, C)
    const float* b  = (const float*)d_in[4];   // (C,)
    float* out = (float*)d_out;

    float* wsf      = (float*)d_ws;
    float* sq       = wsf;                       // N f32
    float* dot0     = wsf + N;                   // N f32
    float* dyrow    = wsf + 2 * N;               // N f32 (||Yi-Y0||^2)
    unsigned* cnt   = (unsigned*)(wsf + 3 * N);  // N u32
    __bf16* xb2     = (__bf16*)(wsf + 4 * N);    // N*D bf16, fragment-major (4 MB)
    __bf16* Wtb2    = (__bf16*)((char*)xb2 + (size_t)N * D * 2); // C*D bf16, frag-major
    double* dacc    = (double*)((char*)Wtb2 + (size_t)C * D * 2);
    unsigned* done  = (unsigned*)(dacc + 2);

    prep_kernel<<<N / 4 + 8, 256, 0, stream>>>(x, Y, W, sq, dot0, dyrow, xb2, Wtb2, cnt, dacc, done);
    fused_mfma<<<NBLK, 256, 0, stream>>>(xb2, Wtb2, sq, dot0, y, b, dyrow, cnt, dacc, done, out);
}